// Round 5
// baseline (643.151 us; speedup 1.0000x reference)
//
#include <hip/hip_runtime.h>

// ---------------------------------------------------------------- types/utils
using bf16x8 = __attribute__((ext_vector_type(8))) short;
using f32x4  = __attribute__((ext_vector_type(4))) float;
using u16x4  = __attribute__((ext_vector_type(4))) unsigned short;

#define AS1(p) ((__attribute__((address_space(1))) void*)(p))
#define AS3(p) ((__attribute__((address_space(3))) void*)(p))

template<int V> struct Ic { static constexpr int value = V; };

__device__ __forceinline__ unsigned short f2bf(float f){
  unsigned int x = __float_as_uint(f);
  unsigned int r = (x + 0x7FFFu + ((x >> 16) & 1u)) >> 16;  // RNE
  return (unsigned short)r;
}
__device__ __forceinline__ float gelu_tanh(float x){
  float u = 0.7978845608028654f * (x + 0.044715f * x * x * x);
  float t = 1.f - 2.f / (__expf(2.f * u) + 1.f);   // tanh(u)
  return 0.5f * x * (1.f + t);
}

// Problem constants
static constexpr int BB = 8, LL = 768, DD = 1024, HH = 4096, TT = 6144;

// ---------------------------------------------------------------- K0: transpose+convert (64x64 tiles)
__global__ __launch_bounds__(256) void k0_transpose(const float* __restrict__ srcE,
                                                    const float* __restrict__ srcS,
                                                    unsigned short* __restrict__ dst,
                                                    int R, int C){
  __shared__ float tile[64][65];
  int z = blockIdx.z;
  const float* src = (z < 4) ? srcE + (size_t)z * R * C : srcS;
  unsigned short* d = dst + (size_t)z * R * C;
  int c0 = blockIdx.x * 64, r0 = blockIdx.y * 64;
  int tx = threadIdx.x & 15, ty = threadIdx.x >> 4;   // 16x16 thread grid
  #pragma unroll
  for (int rep = 0; rep < 4; rep++){
    int r = ty + rep * 16;
    float4 v = *(const float4*)(src + (size_t)(r0 + r) * C + c0 + tx * 4);
    tile[r][tx * 4 + 0] = v.x; tile[r][tx * 4 + 1] = v.y;
    tile[r][tx * 4 + 2] = v.z; tile[r][tx * 4 + 3] = v.w;
  }
  __syncthreads();
  #pragma unroll
  for (int rep = 0; rep < 4; rep++){
    int c = ty + rep * 16;                            // out row (= src col)
    u16x4 o;
    o[0] = f2bf(tile[tx * 4 + 0][c]); o[1] = f2bf(tile[tx * 4 + 1][c]);
    o[2] = f2bf(tile[tx * 4 + 2][c]); o[3] = f2bf(tile[tx * 4 + 3][c]);
    *(u16x4*)(d + (size_t)(c0 + c) * R + r0 + tx * 4) = o;
  }
}

// ---------------------------------------------------------------- K1x: X->bf16 + segment partial sums
__global__ __launch_bounds__(256) void k1x_cvt_partial(const float* __restrict__ X,
                                                       unsigned short* __restrict__ Xb,
                                                       float* __restrict__ part){
  int ch = blockIdx.x, b = blockIdx.y, t = threadIdx.x;
  size_t rowbase = ((size_t)(b * LL + ch * 32)) * DD;
  const float4* src = (const float4*)(X + rowbase);
  u16x4* dst = (u16x4*)(Xb + rowbase);
  float4 s; s.x = s.y = s.z = s.w = 0.f;
  for (int l = 0; l < 32; l++){
    float4 v = src[l * 256 + t];
    u16x4 o;
    o[0] = f2bf(v.x); o[1] = f2bf(v.y); o[2] = f2bf(v.z); o[3] = f2bf(v.w);
    dst[l * 256 + t] = o;
    s.x += v.x; s.y += v.y; s.z += v.z; s.w += v.w;
  }
  ((float4*)(part + ((size_t)(b * 24 + ch)) * DD))[t] = s;
}

// ---------------------------------------------------------------- K1b: gating finalize (fp32)
__global__ __launch_bounds__(256) void k1b_gate(const float* __restrict__ part,
                                                const float* __restrict__ tc,
                                                const float* __restrict__ gw,
                                                const float* __restrict__ gb,
                                                const float* __restrict__ tw,
                                                const float* __restrict__ tb,
                                                float* __restrict__ wtop, int* __restrict__ itop){
  int b = blockIdx.x, t = threadIdx.x;
  __shared__ float glog[4], gmod[8];
  if (t < 4) glog[t] = 0.f;
  if (t < 8) gmod[t] = 0.f;
  __syncthreads();
  float lacc[4] = {0.f,0.f,0.f,0.f};
  float macc[8] = {0.f,0.f,0.f,0.f,0.f,0.f,0.f,0.f};
  for (int dd = 0; dd < 4; dd++){
    int d = dd * 256 + t;
    const float* pb = part + (size_t)b * 24 * DD + d;
    float sh = 0.f, sw = 0.f, sp = 0.f;
    for (int c2 = 0; c2 < 8; c2++){
      sh += pb[(0  + c2) * DD];
      sw += pb[(8  + c2) * DD];
      sp += pb[(16 + c2) * DD];
    }
    float fa = (sh + sw + sp) * (1.f / 768.f);
    float hp = (sh + sp) * (1.f / 512.f);
    float wp = (sw + sp) * (1.f / 512.f);
    #pragma unroll
    for (int e = 0; e < 4; e++){
      lacc[e] += fa * gw[(size_t)d * 4 + e]
               + hp * gw[(size_t)(DD + d) * 4 + e]
               + wp * gw[(size_t)(2 * DD + d) * 4 + e];
    }
    float v = tc[(size_t)b * DD + d];
    float sl = v / (1.f + __expf(-v));           // silu
    #pragma unroll
    for (int j = 0; j < 8; j++) macc[j] += sl * tw[(size_t)d * 8 + j];
  }
  #pragma unroll
  for (int e = 0; e < 4; e++) atomicAdd(&glog[e], lacc[e]);
  #pragma unroll
  for (int j = 0; j < 8; j++) atomicAdd(&gmod[j], macc[j]);
  __syncthreads();
  if (t == 0){
    float lg[4];
    #pragma unroll
    for (int e = 0; e < 4; e++){
      float sc = gmod[e]     + tb[e];      // scale
      float sf = gmod[4 + e] + tb[4 + e];  // shift
      lg[e] = (glog[e] + gb[e]) * (1.f + sc) + sf;
    }
    float mx = fmaxf(fmaxf(lg[0], lg[1]), fmaxf(lg[2], lg[3]));
    float p[4], s = 0.f;
    #pragma unroll
    for (int e = 0; e < 4; e++){ p[e] = __expf(lg[e] - mx); s += p[e]; }
    #pragma unroll
    for (int e = 0; e < 4; e++) p[e] /= s;
    int i0 = 0;
    for (int e = 1; e < 4; e++) if (p[e] > p[i0]) i0 = e;
    int i1 = (i0 == 0) ? 1 : 0;
    for (int e = 0; e < 4; e++) if (e != i0 && p[e] > p[i1]) i1 = e;
    float den = p[i0] + p[i1] + 1e-8f;
    wtop[b * 2 + 0] = p[i0] / den;  wtop[b * 2 + 1] = p[i1] / den;
    itop[b * 2 + 0] = i0;           itop[b * 2 + 1] = i1;
  }
}

// ---------------------------------------------------------------- 256x256 8-phase GEMM core
// C(256x256) += A(256 x 64*nkt) * B^T.  512 thr = 8 waves (2M x 4N); wave
// tile 128x64 = 8x4 MFMA 16x16x32 frags.  LDS 128 KB (2 dbuf x 2 half x 16KB
// x {A,B}) -> 1 block/CU, 2 waves/SIMD.
//
// LDS swizzle (G4, both-sides): full-row XOR byte ^= ((row&7)<<4); linear
// global_load_lds dest + pre-swizzled GLOBAL source; ds_read same XOR.
// Verified round 3: SQ_LDS_BANK_CONFLICT == 0.
//
// K-loop is unrolled in PAIRS of K-tiles (8 phases / pair) so BUF is
// compile-time per copy: constant LDS bases (ds offset-imm folding) and
// cross-K-tile compiler scheduling (m201 template fidelity; runtime buf
// indexing was the round-4 residual difference).  Steady-state body is
// branch-free (all prefetch predicates true); tail pair peeled.
// Per K-tile phases (audited r1): P0 {ldA0,ldB0 | stA(buf^1,1,kt+1)},
// P1 {ldB1 | stA(buf,0,kt+2)}, P2 {ldA1 | stB(buf,0,kt+2)},
// P3 {— | stB(buf,1,kt+2)}; each phase: barrier, setprio(1), 16 MFMA,
// setprio(0), barrier; counted vmcnt(6) once per K-tile at P3 (never 0 in
// steady state), tail drains.
#define MMA_Q(AF, BQ, MH, NH)                                                   \
  {                                                                             \
    _Pragma("unroll") for (int ks = 0; ks < 2; ks++)                            \
    _Pragma("unroll") for (int mf = 0; mf < 4; mf++)                            \
    _Pragma("unroll") for (int nf = 0; nf < 2; nf++)                            \
      acc[(MH)*4+mf][(NH)*2+nf] = __builtin_amdgcn_mfma_f32_16x16x32_bf16(      \
          (AF)[mf][ks], (BQ)[nf][ks], acc[(MH)*4+mf][(NH)*2+nf], 0, 0, 0);      \
  }

__device__ __forceinline__ void gemm256_core(const unsigned short* __restrict__ A,
                                             const unsigned short* __restrict__ B,
                                             int lda, int ldb, int nkt,
                                             unsigned short* ldsA,
                                             unsigned short* ldsB,
                                             f32x4 (&acc)[8][4]){
  const int t = threadIdx.x;
  const int lane = t & 63, quad = lane >> 4, r = lane & 15;
  const int wave = t >> 6, wm = wave >> 2, wn = wave & 3;
  const int welem = (t & 448) * 8;           // wave*512 elements within a half

  // staging source coords (pre-swizzled global so linear LDS ends up swizzled)
  int offA[2], offB[2];
  #pragma unroll
  for (int j = 0; j < 2; j++){
    int x = t * 16 + j * 8192;               // linear byte in 16KB half-tile
    int y = x ^ (((x >> 7) & 7) << 4);       // (row&7)<<4 involution
    int cr = y >> 7, kel = (y & 127) >> 1;   // compact row, k element
    offA[j] = (((cr >> 6) << 7) + (cr & 63)) * lda + kel;
    offB[j] = (((cr >> 5) << 6) + (cr & 31)) * ldb + kel;
  }
  const int ldam = 64 * lda, ldbn = 32 * ldb;

  auto stA = [&](int buf, int mh, int kt){
    #pragma unroll
    for (int j = 0; j < 2; j++)
      __builtin_amdgcn_global_load_lds(AS1(A + offA[j] + mh * ldam + kt * 64),
          AS3(ldsA + (buf * 2 + mh) * 8192 + welem + j * 4096), 16, 0, 0);
  };
  auto stB = [&](int buf, int nh, int kt){
    #pragma unroll
    for (int j = 0; j < 2; j++)
      __builtin_amdgcn_global_load_lds(AS1(B + offB[j] + nh * ldbn + kt * 64),
          AS3(ldsB + (buf * 2 + nh) * 8192 + welem + j * 4096), 16, 0, 0);
  };
  auto ldA = [&](int buf, int mh, bf16x8 (&dst)[4][2]){
    #pragma unroll
    for (int mf = 0; mf < 4; mf++){
      int cr = wm * 64 + mf * 16 + r;
      const unsigned short* p = ldsA + (buf * 2 + mh) * 8192 + cr * 64;
      int sw = (cr & 7) << 3;                // element-space row swizzle
      dst[mf][0] = *(const bf16x8*)(p + ((quad * 8) ^ sw));
      dst[mf][1] = *(const bf16x8*)(p + ((32 + quad * 8) ^ sw));
    }
  };
  auto ldB = [&](int buf, int nh, bf16x8 (&dst)[2][2]){
    #pragma unroll
    for (int nf = 0; nf < 2; nf++){
      int cc = wn * 32 + nf * 16 + r;
      const unsigned short* p = ldsB + (buf * 2 + nh) * 8192 + cc * 64;
      int sw = (cc & 7) << 3;
      dst[nf][0] = *(const bf16x8*)(p + ((quad * 8) ^ sw));
      dst[nf][1] = *(const bf16x8*)(p + ((32 + quad * 8) ^ sw));
    }
  };

  // one K-tile, BUF compile-time
  auto ktile = [&](auto bufc, int kt, bool pf1, bool pf2){
    constexpr int BUF = decltype(bufc)::value;
    bf16x8 af[4][2], b0[2][2], b1[2][2];
    // ---- P0: quadrant (mh0, nh0)
    ldA(BUF, 0, af); ldB(BUF, 0, b0);
    if (pf1) stA(BUF ^ 1, 1, kt + 1);
    __builtin_amdgcn_s_barrier();
    __builtin_amdgcn_s_setprio(1);
    MMA_Q(af, b0, 0, 0);
    __builtin_amdgcn_s_setprio(0);
    __builtin_amdgcn_s_barrier();
    // ---- P1: quadrant (mh0, nh1)
    ldB(BUF, 1, b1);
    if (pf2) stA(BUF, 0, kt + 2);
    __builtin_amdgcn_s_barrier();
    __builtin_amdgcn_s_setprio(1);
    MMA_Q(af, b1, 0, 1);
    __builtin_amdgcn_s_setprio(0);
    __builtin_amdgcn_s_barrier();
    // ---- P2: quadrant (mh1, nh1)
    ldA(BUF, 1, af);
    if (pf2) stB(BUF, 0, kt + 2);
    __builtin_amdgcn_s_barrier();
    __builtin_amdgcn_s_setprio(1);
    MMA_Q(af, b1, 1, 1);
    __builtin_amdgcn_s_setprio(0);
    __builtin_amdgcn_s_barrier();
    // ---- P3: quadrant (mh1, nh0)
    if (pf2) stB(BUF, 1, kt + 2);
    __builtin_amdgcn_s_barrier();
    __builtin_amdgcn_s_setprio(1);
    MMA_Q(af, b0, 1, 0);
    __builtin_amdgcn_s_setprio(0);
    if (pf1){                                  // K-tile boundary wait
      if (pf2) asm volatile("s_waitcnt vmcnt(6)" ::: "memory");
      else     asm volatile("s_waitcnt vmcnt(0)" ::: "memory");
    }
    __builtin_amdgcn_s_barrier();
  };

  // prologue: kt0 {A0,B0,B1,A1}, kt1 {A0,B0,B1} -- order matters for vmcnt
  stA(0, 0, 0); stB(0, 0, 0); stB(0, 1, 0); stA(0, 1, 0);
  stA(1, 0, 1); stB(1, 0, 1); stB(1, 1, 1);
  asm volatile("s_waitcnt vmcnt(6)" ::: "memory");   // kt0's 8 loads landed
  __builtin_amdgcn_s_barrier();

  int kt = 0;
  for (; kt + 2 < nkt; kt += 2){             // steady-state pairs, branch-free
    ktile(Ic<0>{}, kt,     true, true);
    ktile(Ic<1>{}, kt + 1, true, true);
  }
  ktile(Ic<0>{}, nkt - 2, true,  false);     // tail pair: drain
  ktile(Ic<1>{}, nkt - 1, false, false);
}

__device__ __forceinline__ void mask_weight(int e, int seg, float& w){
  if ((e == 1 && seg == 1) || (e == 2 && seg == 0)) w = 0.f;
}

// bijective XCD swizzle (T1, m204 form; requires nwg % 8 == 0 -- both grids
// are): consecutive swizzled ids land on ONE XCD, bx-fastest decode keeps a
// B-panel's 24 m-tiles (k3a) / <=6 panels (k2) in one XCD's L2.
template<int GX, int GY>
__device__ __forceinline__ void xcd_swizzle(int& bx, int& by, int& bz){
  int lin = blockIdx.x + GX * (blockIdx.y + GY * blockIdx.z);
  int nwg = GX * GY * gridDim.z;
  int q = nwg >> 3;
  int swz = (lin & 7) * q + (lin >> 3);
  bx = swz % GX; int rem = swz / GX; by = rem % GY; bz = rem / GY;
}

// ---------------------------------------------------------------- K2: GEMM1 + gelu
__global__ __launch_bounds__(512, 2) void k2_gemm1(const unsigned short* __restrict__ Xb,
                                                   const unsigned short* __restrict__ w1t,
                                                   const float* __restrict__ eb1,
                                                   const float* __restrict__ sb1,
                                                   const float* __restrict__ wtop,
                                                   const int* __restrict__ itop,
                                                   unsigned short* __restrict__ Hws){
  int bx, by, bz; xcd_swizzle<24, 16>(bx, by, bz);
  int m0 = bx * 256, n0 = by * 256, slot = bz;
  int b = m0 / LL, seg = (m0 % LL) / 256;
  int mat; float w;
  if (slot == 0){ mat = 4; w = 1.f; }
  else {
    int k = slot - 1;
    mat = itop[b * 2 + k];
    w = wtop[b * 2 + k];
    mask_weight(mat, seg, w);
    if (w == 0.f) return;  // K3a skips this (m-tile, slot) with the same predicate
  }
  __shared__ __align__(16) unsigned short ldsA[32768];
  __shared__ __align__(16) unsigned short ldsB[32768];
  f32x4 acc[8][4];
  #pragma unroll
  for (int mi = 0; mi < 8; mi++)
    #pragma unroll
    for (int ni = 0; ni < 4; ni++)
      #pragma unroll
      for (int c = 0; c < 4; c++) acc[mi][ni][c] = 0.f;

  gemm256_core(Xb + (size_t)m0 * DD,
               w1t + (size_t)mat * HH * DD + (size_t)n0 * DD,
               DD, DD, DD / 64, ldsA, ldsB, acc);

  int t = threadIdx.x, lane = t & 63, wave = t >> 6;
  int quad = lane >> 4, r = lane & 15, wm = wave >> 2, wn = wave & 3;
  const float* b1 = (mat == 4) ? sb1 : eb1 + (size_t)mat * HH;
  unsigned short* Hout = Hws + (size_t)slot * TT * HH;
  #pragma unroll
  for (int ni = 0; ni < 4; ni++){
    int col = n0 + wn * 64 + ni * 16 + r;
    float bias = b1[col];
    #pragma unroll
    for (int mi = 0; mi < 8; mi++){
      #pragma unroll
      for (int r2 = 0; r2 < 4; r2++){
        int row = m0 + wm * 128 + mi * 16 + quad * 4 + r2;
        Hout[(size_t)row * HH + col] = f2bf(gelu_tanh(acc[mi][ni][r2] + bias) * w);
      }
    }
  }
}

// ---------------------------------------------------------------- K3a: GEMM2, slots in-block, z=K-half
__global__ __launch_bounds__(512, 2) void k3a_gemm2(const unsigned short* __restrict__ Hws,
                                                    const unsigned short* __restrict__ w2t,
                                                    const float* __restrict__ eb2,
                                                    const float* __restrict__ sb2,
                                                    const float* __restrict__ wtop,
                                                    const int* __restrict__ itop,
                                                    float* __restrict__ out,
                                                    float* __restrict__ p1){
  int bx, by, bz; xcd_swizzle<24, 4>(bx, by, bz);
  int m0 = bx * 256, n0 = by * 256, kh = bz;
  int b = m0 / LL, seg = (m0 % LL) / 256;
  __shared__ __align__(16) unsigned short ldsA[32768];
  __shared__ __align__(16) unsigned short ldsB[32768];
  f32x4 acc[8][4];
  #pragma unroll
  for (int mi = 0; mi < 8; mi++)
    #pragma unroll
    for (int ni = 0; ni < 4; ni++)
      #pragma unroll
      for (int c = 0; c < 4; c++) acc[mi][ni][c] = 0.f;

  int emat[2]; float ew[2];
  #pragma unroll
  for (int k = 0; k < 2; k++){
    emat[k] = itop[b * 2 + k];
    ew[k] = wtop[b * 2 + k];
    mask_weight(emat[k], seg, ew[k]);
  }
  for (int slot = 0; slot < 3; slot++){
    int mat;
    if (slot == 0) mat = 4;
    else { if (ew[slot - 1] == 0.f) continue; mat = emat[slot - 1]; }  // matches K2 skip
    gemm256_core(Hws + (size_t)slot * TT * HH + (size_t)m0 * HH + kh * 2048,
                 w2t + (size_t)mat * DD * HH + (size_t)n0 * HH + kh * 2048,
                 HH, HH, 2048 / 64, ldsA, ldsB, acc);
  }
  int t = threadIdx.x, lane = t & 63, wave = t >> 6;
  int quad = lane >> 4, r = lane & 15, wm = wave >> 2, wn = wave & 3;
  if (kh == 0){
    #pragma unroll
    for (int ni = 0; ni < 4; ni++){
      int col = n0 + wn * 64 + ni * 16 + r;
      float bias = sb2[col];
      if (ew[0] > 0.f) bias += ew[0] * eb2[(size_t)emat[0] * DD + col];
      if (ew[1] > 0.f) bias += ew[1] * eb2[(size_t)emat[1] * DD + col];
      #pragma unroll
      for (int mi = 0; mi < 8; mi++)
        #pragma unroll
        for (int r2 = 0; r2 < 4; r2++){
          int row = m0 + wm * 128 + mi * 16 + quad * 4 + r2;
          out[(size_t)row * DD + col] = acc[mi][ni][r2] + bias;
        }
    }
  } else {
    #pragma unroll
    for (int ni = 0; ni < 4; ni++){
      int col = n0 + wn * 64 + ni * 16 + r;
      #pragma unroll
      for (int mi = 0; mi < 8; mi++)
        #pragma unroll
        for (int r2 = 0; r2 < 4; r2++){
          int row = m0 + wm * 128 + mi * 16 + quad * 4 + r2;
          p1[(size_t)row * DD + col] = acc[mi][ni][r2];
        }
    }
  }
}

// ---------------------------------------------------------------- K3r: out += p1
__global__ __launch_bounds__(256) void k3r_reduce(float* __restrict__ out,
                                                  const float* __restrict__ p1){
  size_t i = (size_t)blockIdx.x * 256 + threadIdx.x;
  float4 a = ((const float4*)out)[i];
  float4 b = ((const float4*)p1)[i];
  a.x += b.x; a.y += b.y; a.z += b.z; a.w += b.w;
  ((float4*)out)[i] = a;
}

// ---------------------------------------------------------------- launch
extern "C" void kernel_launch(void* const* d_in, const int* in_sizes, int n_in,
                              void* d_out, int out_size, void* d_ws, size_t ws_size,
                              hipStream_t stream){
  const float* X   = (const float*)d_in[0];   // context_c (8,768,1024)
  const float* tc  = (const float*)d_in[1];   // time_cond (8,1024)
  const float* gw  = (const float*)d_in[2];   // gate_w (3072,4)
  const float* gb  = (const float*)d_in[3];   // gate_b (4)
  const float* tw  = (const float*)d_in[4];   // time_w (1024,8)
  const float* tb  = (const float*)d_in[5];   // time_b (8)
  const float* ew1 = (const float*)d_in[6];   // (4,1024,4096)
  const float* eb1 = (const float*)d_in[7];   // (4,4096)
  const float* ew2 = (const float*)d_in[8];   // (4,4096,1024)
  const float* eb2 = (const float*)d_in[9];   // (4,1024)
  const float* sw1 = (const float*)d_in[10];  // (1024,4096)
  const float* sb1 = (const float*)d_in[11];  // (4096)
  const float* sw2 = (const float*)d_in[12];  // (4096,1024)
  const float* sb2 = (const float*)d_in[13];  // (1024)
  float* out = (float*)d_out;
  char* ws = (char*)d_ws;

  const size_t off_part = 0;                         // 8*24*1024*4 = 786432
  const size_t off_wtop = 786432;                    // 64 B
  const size_t off_itop = 786560;                    // 64 B
  const size_t off_xb   = 1ull << 20;                // 6144*1024*2 = 12,582,912
  const size_t off_w1t  = 14ull << 20;               // 5*4096*1024*2 = 41,943,040
  const size_t off_w2t  = off_w1t + 41943040ull;     // 41,943,040
  const size_t off_h    = off_w2t + 41943040ull;     // 3*6144*4096*2 = 150,994,944
  const size_t need     = off_h + 150994944ull;      // ~238 MiB
  if (ws_size < need) return;

  float* part = (float*)(ws + off_part);
  float* wtop = (float*)(ws + off_wtop);
  int*   itop = (int*)(ws + off_itop);
  unsigned short* Xb  = (unsigned short*)(ws + off_xb);
  unsigned short* w1t = (unsigned short*)(ws + off_w1t);
  unsigned short* w2t = (unsigned short*)(ws + off_w2t);
  unsigned short* Hws = (unsigned short*)(ws + off_h);
  float* p1 = (float*)(ws + off_w1t);  // aliases w1t: dead after k2, reused by k3a

  // K1x: X fp32 -> bf16 + gating partial sums (single pass over X)
  k1x_cvt_partial<<<dim3(24, 8), 256, 0, stream>>>(X, Xb, part);
  // K0: weight transpose+convert
  k0_transpose<<<dim3(64, 16, 5), 256, 0, stream>>>(ew1, sw1, w1t, 1024, 4096);
  k0_transpose<<<dim3(16, 64, 5), 256, 0, stream>>>(ew2, sw2, w2t, 4096, 1024);
  // K1b: gating finalize (fp32 exact)
  k1b_gate<<<dim3(8), 256, 0, stream>>>(part, tc, gw, gb, tw, tb, wtop, itop);
  // K2: X @ W1 + b1 -> gelu -> *w_eff -> H (3 slots); 256^2 8-phase core
  k2_gemm1<<<dim3(24, 16, 3), 512, 0, stream>>>(Xb, w1t, eb1, sb1, wtop, itop, Hws);
  // K3a: slots in-block, z = K-half; kh=0 -> out(+bias), kh=1 -> p1
  k3a_gemm2<<<dim3(24, 4, 2), 512, 0, stream>>>(Hws, w2t, eb2, sb2, wtop, itop, out, p1);
  // K3r: out += p1
  k3r_reduce<<<dim3(6144), 256, 0, stream>>>(out, p1);
}

// Round 7
// 625.452 us; speedup vs baseline: 1.0283x; 1.0283x over previous
//
#include <hip/hip_runtime.h>

// ---------------------------------------------------------------- types/utils
using bf16x8 = __attribute__((ext_vector_type(8))) short;
using f32x4  = __attribute__((ext_vector_type(4))) float;
using u16x4  = __attribute__((ext_vector_type(4))) unsigned short;
using u16x8  = __attribute__((ext_vector_type(8))) unsigned short;

#define AS1(p) ((__attribute__((address_space(1))) void*)(p))
#define AS3(p) ((__attribute__((address_space(3))) void*)(p))

template<int V> struct Ic { static constexpr int value = V; };

__device__ __forceinline__ unsigned short f2bf(float f){
  unsigned int x = __float_as_uint(f);
  unsigned int r = (x + 0x7FFFu + ((x >> 16) & 1u)) >> 16;  // RNE
  return (unsigned short)r;
}
__device__ __forceinline__ float gelu_tanh(float x){
  float u = 0.7978845608028654f * (x + 0.044715f * x * x * x);
  float t = 1.f - 2.f / (__expf(2.f * u) + 1.f);   // tanh(u)
  return 0.5f * x * (1.f + t);
}

// Problem constants
static constexpr int BB = 8, LL = 768, DD = 1024, HH = 4096, TT = 6144;

// ---------------------------------------------------------------- K0: transpose+convert (64x64 tiles)
__global__ __launch_bounds__(256) void k0_transpose(const float* __restrict__ srcE,
                                                    const float* __restrict__ srcS,
                                                    unsigned short* __restrict__ dst,
                                                    int R, int C){
  __shared__ float tile[64][65];
  int z = blockIdx.z;
  const float* src = (z < 4) ? srcE + (size_t)z * R * C : srcS;
  unsigned short* d = dst + (size_t)z * R * C;
  int c0 = blockIdx.x * 64, r0 = blockIdx.y * 64;
  int tx = threadIdx.x & 15, ty = threadIdx.x >> 4;   // 16x16 thread grid
  #pragma unroll
  for (int rep = 0; rep < 4; rep++){
    int r = ty + rep * 16;
    float4 v = *(const float4*)(src + (size_t)(r0 + r) * C + c0 + tx * 4);
    tile[r][tx * 4 + 0] = v.x; tile[r][tx * 4 + 1] = v.y;
    tile[r][tx * 4 + 2] = v.z; tile[r][tx * 4 + 3] = v.w;
  }
  __syncthreads();
  #pragma unroll
  for (int rep = 0; rep < 4; rep++){
    int c = ty + rep * 16;                            // out row (= src col)
    u16x4 o;
    o[0] = f2bf(tile[tx * 4 + 0][c]); o[1] = f2bf(tile[tx * 4 + 1][c]);
    o[2] = f2bf(tile[tx * 4 + 2][c]); o[3] = f2bf(tile[tx * 4 + 3][c]);
    *(u16x4*)(d + (size_t)(c0 + c) * R + r0 + tx * 4) = o;
  }
}

// ---------------------------------------------------------------- K1x: X->bf16 + segment partial sums
__global__ __launch_bounds__(256) void k1x_cvt_partial(const float* __restrict__ X,
                                                       unsigned short* __restrict__ Xb,
                                                       float* __restrict__ part){
  int ch = blockIdx.x, b = blockIdx.y, t = threadIdx.x;
  size_t rowbase = ((size_t)(b * LL + ch * 32)) * DD;
  const float4* src = (const float4*)(X + rowbase);
  u16x4* dst = (u16x4*)(Xb + rowbase);
  float4 s; s.x = s.y = s.z = s.w = 0.f;
  for (int l = 0; l < 32; l++){
    float4 v = src[l * 256 + t];
    u16x4 o;
    o[0] = f2bf(v.x); o[1] = f2bf(v.y); o[2] = f2bf(v.z); o[3] = f2bf(v.w);
    dst[l * 256 + t] = o;
    s.x += v.x; s.y += v.y; s.z += v.z; s.w += v.w;
  }
  ((float4*)(part + ((size_t)(b * 24 + ch)) * DD))[t] = s;
}

// ---------------------------------------------------------------- K1b: gating finalize (fp32)
__global__ __launch_bounds__(256) void k1b_gate(const float* __restrict__ part,
                                                const float* __restrict__ tc,
                                                const float* __restrict__ gw,
                                                const float* __restrict__ gb,
                                                const float* __restrict__ tw,
                                                const float* __restrict__ tb,
                                                float* __restrict__ wtop, int* __restrict__ itop){
  int b = blockIdx.x, t = threadIdx.x;
  __shared__ float glog[4], gmod[8];
  if (t < 4) glog[t] = 0.f;
  if (t < 8) gmod[t] = 0.f;
  __syncthreads();
  float lacc[4] = {0.f,0.f,0.f,0.f};
  float macc[8] = {0.f,0.f,0.f,0.f,0.f,0.f,0.f,0.f};
  for (int dd = 0; dd < 4; dd++){
    int d = dd * 256 + t;
    const float* pb = part + (size_t)b * 24 * DD + d;
    float sh = 0.f, sw = 0.f, sp = 0.f;
    for (int c2 = 0; c2 < 8; c2++){
      sh += pb[(0  + c2) * DD];
      sw += pb[(8  + c2) * DD];
      sp += pb[(16 + c2) * DD];
    }
    float fa = (sh + sw + sp) * (1.f / 768.f);
    float hp = (sh + sp) * (1.f / 512.f);
    float wp = (sw + sp) * (1.f / 512.f);
    #pragma unroll
    for (int e = 0; e < 4; e++){
      lacc[e] += fa * gw[(size_t)d * 4 + e]
               + hp * gw[(size_t)(DD + d) * 4 + e]
               + wp * gw[(size_t)(2 * DD + d) * 4 + e];
    }
    float v = tc[(size_t)b * DD + d];
    float sl = v / (1.f + __expf(-v));           // silu
    #pragma unroll
    for (int j = 0; j < 8; j++) macc[j] += sl * tw[(size_t)d * 8 + j];
  }
  #pragma unroll
  for (int e = 0; e < 4; e++) atomicAdd(&glog[e], lacc[e]);
  #pragma unroll
  for (int j = 0; j < 8; j++) atomicAdd(&gmod[j], macc[j]);
  __syncthreads();
  if (t == 0){
    float lg[4];
    #pragma unroll
    for (int e = 0; e < 4; e++){
      float sc = gmod[e]     + tb[e];      // scale
      float sf = gmod[4 + e] + tb[4 + e];  // shift
      lg[e] = (glog[e] + gb[e]) * (1.f + sc) + sf;
    }
    float mx = fmaxf(fmaxf(lg[0], lg[1]), fmaxf(lg[2], lg[3]));
    float p[4], s = 0.f;
    #pragma unroll
    for (int e = 0; e < 4; e++){ p[e] = __expf(lg[e] - mx); s += p[e]; }
    #pragma unroll
    for (int e = 0; e < 4; e++) p[e] /= s;
    int i0 = 0;
    for (int e = 1; e < 4; e++) if (p[e] > p[i0]) i0 = e;
    int i1 = (i0 == 0) ? 1 : 0;
    for (int e = 0; e < 4; e++) if (e != i0 && p[e] > p[i1]) i1 = e;
    float den = p[i0] + p[i1] + 1e-8f;
    wtop[b * 2 + 0] = p[i0] / den;  wtop[b * 2 + 1] = p[i1] / den;
    itop[b * 2 + 0] = i0;           itop[b * 2 + 1] = i1;
  }
}

// ---------------------------------------------------------------- 256x256 8-phase GEMM core
// (structure unchanged from round 4/5 — audited; SQ_LDS_BANK_CONFLICT == 0)
#define MMA_Q(AF, BQ, MH, NH)                                                   \
  {                                                                             \
    _Pragma("unroll") for (int ks = 0; ks < 2; ks++)                            \
    _Pragma("unroll") for (int mf = 0; mf < 4; mf++)                            \
    _Pragma("unroll") for (int nf = 0; nf < 2; nf++)                            \
      acc[(MH)*4+mf][(NH)*2+nf] = __builtin_amdgcn_mfma_f32_16x16x32_bf16(      \
          (AF)[mf][ks], (BQ)[nf][ks], acc[(MH)*4+mf][(NH)*2+nf], 0, 0, 0);      \
  }

__device__ __forceinline__ void gemm256_core(const unsigned short* __restrict__ A,
                                             const unsigned short* __restrict__ B,
                                             int lda, int ldb, int nkt,
                                             unsigned short* ldsA,
                                             unsigned short* ldsB,
                                             f32x4 (&acc)[8][4]){
  const int t = threadIdx.x;
  const int lane = t & 63, quad = lane >> 4, r = lane & 15;
  const int wave = t >> 6, wm = wave >> 2, wn = wave & 3;
  const int welem = (t & 448) * 8;           // wave*512 elements within a half

  // staging source coords (pre-swizzled global so linear LDS ends up swizzled)
  int offA[2], offB[2];
  #pragma unroll
  for (int j = 0; j < 2; j++){
    int x = t * 16 + j * 8192;               // linear byte in 16KB half-tile
    int y = x ^ (((x >> 7) & 7) << 4);       // (row&7)<<4 involution
    int cr = y >> 7, kel = (y & 127) >> 1;   // compact row, k element
    offA[j] = (((cr >> 6) << 7) + (cr & 63)) * lda + kel;
    offB[j] = (((cr >> 5) << 6) + (cr & 31)) * ldb + kel;
  }
  const int ldam = 64 * lda, ldbn = 32 * ldb;

  auto stA = [&](int buf, int mh, int kt){
    #pragma unroll
    for (int j = 0; j < 2; j++)
      __builtin_amdgcn_global_load_lds(AS1(A + offA[j] + mh * ldam + kt * 64),
          AS3(ldsA + (buf * 2 + mh) * 8192 + welem + j * 4096), 16, 0, 0);
  };
  auto stB = [&](int buf, int nh, int kt){
    #pragma unroll
    for (int j = 0; j < 2; j++)
      __builtin_amdgcn_global_load_lds(AS1(B + offB[j] + nh * ldbn + kt * 64),
          AS3(ldsB + (buf * 2 + nh) * 8192 + welem + j * 4096), 16, 0, 0);
  };
  auto ldA = [&](int buf, int mh, bf16x8 (&dst)[4][2]){
    #pragma unroll
    for (int mf = 0; mf < 4; mf++){
      int cr = wm * 64 + mf * 16 + r;
      const unsigned short* p = ldsA + (buf * 2 + mh) * 8192 + cr * 64;
      int sw = (cr & 7) << 3;                // element-space row swizzle
      dst[mf][0] = *(const bf16x8*)(p + ((quad * 8) ^ sw));
      dst[mf][1] = *(const bf16x8*)(p + ((32 + quad * 8) ^ sw));
    }
  };
  auto ldB = [&](int buf, int nh, bf16x8 (&dst)[2][2]){
    #pragma unroll
    for (int nf = 0; nf < 2; nf++){
      int cc = wn * 32 + nf * 16 + r;
      const unsigned short* p = ldsB + (buf * 2 + nh) * 8192 + cc * 64;
      int sw = (cc & 7) << 3;
      dst[nf][0] = *(const bf16x8*)(p + ((quad * 8) ^ sw));
      dst[nf][1] = *(const bf16x8*)(p + ((32 + quad * 8) ^ sw));
    }
  };

  // one K-tile, BUF compile-time
  auto ktile = [&](auto bufc, int kt, bool pf1, bool pf2){
    constexpr int BUF = decltype(bufc)::value;
    bf16x8 af[4][2], b0[2][2], b1[2][2];
    // ---- P0: quadrant (mh0, nh0)
    ldA(BUF, 0, af); ldB(BUF, 0, b0);
    if (pf1) stA(BUF ^ 1, 1, kt + 1);
    __builtin_amdgcn_s_barrier();
    __builtin_amdgcn_s_setprio(1);
    MMA_Q(af, b0, 0, 0);
    __builtin_amdgcn_s_setprio(0);
    __builtin_amdgcn_s_barrier();
    // ---- P1: quadrant (mh0, nh1)
    ldB(BUF, 1, b1);
    if (pf2) stA(BUF, 0, kt + 2);
    __builtin_amdgcn_s_barrier();
    __builtin_amdgcn_s_setprio(1);
    MMA_Q(af, b1, 0, 1);
    __builtin_amdgcn_s_setprio(0);
    __builtin_amdgcn_s_barrier();
    // ---- P2: quadrant (mh1, nh1)
    ldA(BUF, 1, af);
    if (pf2) stB(BUF, 0, kt + 2);
    __builtin_amdgcn_s_barrier();
    __builtin_amdgcn_s_setprio(1);
    MMA_Q(af, b1, 1, 1);
    __builtin_amdgcn_s_setprio(0);
    __builtin_amdgcn_s_barrier();
    // ---- P3: quadrant (mh1, nh0)
    if (pf2) stB(BUF, 1, kt + 2);
    __builtin_amdgcn_s_barrier();
    __builtin_amdgcn_s_setprio(1);
    MMA_Q(af, b0, 1, 0);
    __builtin_amdgcn_s_setprio(0);
    if (pf1){                                  // K-tile boundary wait
      if (pf2) asm volatile("s_waitcnt vmcnt(6)" ::: "memory");
      else     asm volatile("s_waitcnt vmcnt(0)" ::: "memory");
    }
    __builtin_amdgcn_s_barrier();
  };

  // prologue: kt0 {A0,B0,B1,A1}, kt1 {A0,B0,B1} -- order matters for vmcnt
  stA(0, 0, 0); stB(0, 0, 0); stB(0, 1, 0); stA(0, 1, 0);
  stA(1, 0, 1); stB(1, 0, 1); stB(1, 1, 1);
  asm volatile("s_waitcnt vmcnt(6)" ::: "memory");   // kt0's 8 loads landed
  __builtin_amdgcn_s_barrier();

  int kt = 0;
  for (; kt + 2 < nkt; kt += 2){             // steady-state pairs, branch-free
    ktile(Ic<0>{}, kt,     true, true);
    ktile(Ic<1>{}, kt + 1, true, true);
  }
  ktile(Ic<0>{}, nkt - 2, true,  false);     // tail pair: drain
  ktile(Ic<1>{}, nkt - 1, false, false);
}

__device__ __forceinline__ void mask_weight(int e, int seg, float& w){
  if ((e == 1 && seg == 1) || (e == 2 && seg == 0)) w = 0.f;
}

// ---------------------------------------------------------------- K2: GEMM1 + gelu
__global__ __launch_bounds__(512, 2) void k2_gemm1(const unsigned short* __restrict__ Xb,
                                                   const unsigned short* __restrict__ w1t,
                                                   const float* __restrict__ eb1,
                                                   const float* __restrict__ sb1,
                                                   const float* __restrict__ wtop,
                                                   const int* __restrict__ itop,
                                                   unsigned short* __restrict__ Hws){
  int m0 = blockIdx.x * 256, n0 = blockIdx.y * 256, slot = blockIdx.z;
  int b = m0 / LL, seg = (m0 % LL) / 256;
  int mat; float w;
  if (slot == 0){ mat = 4; w = 1.f; }
  else {
    int k = slot - 1;
    mat = itop[b * 2 + k];
    w = wtop[b * 2 + k];
    mask_weight(mat, seg, w);
    if (w == 0.f) return;  // K3a skips this (m-tile, slot) with the same predicate
  }
  // single 128KB LDS block: [0,32K) = A, [32K,64K) elems = B during the loop;
  // the WHOLE array is reused as the output staging tile in the epilogue.
  __shared__ __align__(16) unsigned short lds[65536];
  unsigned short* ldsA = lds;
  unsigned short* ldsB = lds + 32768;
  f32x4 acc[8][4];
  #pragma unroll
  for (int mi = 0; mi < 8; mi++)
    #pragma unroll
    for (int ni = 0; ni < 4; ni++)
      #pragma unroll
      for (int c = 0; c < 4; c++) acc[mi][ni][c] = 0.f;

  gemm256_core(Xb + (size_t)m0 * DD,
               w1t + (size_t)mat * HH * DD + (size_t)n0 * DD,
               DD, DD, DD / 64, ldsA, ldsB, acc);

  int t = threadIdx.x, lane = t & 63, wave = t >> 6;
  int quad = lane >> 4, r = lane & 15, wm = wave >> 2, wn = wave & 3;
  const float* b1 = (mat == 4) ? sb1 : eb1 + (size_t)mat * HH;
  unsigned short* Hout = Hws + (size_t)slot * TT * HH;
  // ---- epilogue: coalesce bf16 writes via LDS (kills 2x partial-line
  // write amplification: 32B scattered segments -> 512B contiguous rows).
  __syncthreads();                           // loop LDS dead; reuse as out tile
  #pragma unroll
  for (int ni = 0; ni < 4; ni++){
    int col = wn * 64 + ni * 16 + r;         // tile-local col
    float bias = b1[n0 + col];
    #pragma unroll
    for (int mi = 0; mi < 8; mi++){
      #pragma unroll
      for (int r2 = 0; r2 < 4; r2++){
        int row = wm * 128 + mi * 16 + quad * 4 + r2;   // tile-local row
        lds[row * 256 + col] = f2bf(gelu_tanh(acc[mi][ni][r2] + bias) * w);
      }
    }
  }
  __syncthreads();
  // stream out: 256 rows x 512B; each row written as 32 x 16B contiguous.
  #pragma unroll
  for (int it = 0; it < 16; it++){
    int chunk = it * 512 + t;                // [0, 8192)
    int row = chunk >> 5, sg = chunk & 31;
    u16x8 v = *(const u16x8*)(lds + row * 256 + sg * 8);
    *(u16x8*)(Hout + (size_t)(m0 + row) * HH + n0 + sg * 8) = v;
  }
}

// ---------------------------------------------------------------- K3a: GEMM2, slots in-block, z=K-half
__global__ __launch_bounds__(512, 2) void k3a_gemm2(const unsigned short* __restrict__ Hws,
                                                    const unsigned short* __restrict__ w2t,
                                                    const float* __restrict__ eb2,
                                                    const float* __restrict__ sb2,
                                                    const float* __restrict__ wtop,
                                                    const int* __restrict__ itop,
                                                    float* __restrict__ out,
                                                    float* __restrict__ p1){
  int m0 = blockIdx.x * 256, n0 = blockIdx.y * 256, kh = blockIdx.z;
  int b = m0 / LL, seg = (m0 % LL) / 256;
  __shared__ __align__(16) unsigned short ldsA[32768];
  __shared__ __align__(16) unsigned short ldsB[32768];
  f32x4 acc[8][4];
  #pragma unroll
  for (int mi = 0; mi < 8; mi++)
    #pragma unroll
    for (int ni = 0; ni < 4; ni++)
      #pragma unroll
      for (int c = 0; c < 4; c++) acc[mi][ni][c] = 0.f;

  int emat[2]; float ew[2];
  #pragma unroll
  for (int k = 0; k < 2; k++){
    emat[k] = itop[b * 2 + k];
    ew[k] = wtop[b * 2 + k];
    mask_weight(emat[k], seg, ew[k]);
  }
  for (int slot = 0; slot < 3; slot++){
    int mat;
    if (slot == 0) mat = 4;
    else { if (ew[slot - 1] == 0.f) continue; mat = emat[slot - 1]; }  // matches K2 skip
    gemm256_core(Hws + (size_t)slot * TT * HH + (size_t)m0 * HH + kh * 2048,
                 w2t + (size_t)mat * DD * HH + (size_t)n0 * HH + kh * 2048,
                 HH, HH, 2048 / 64, ldsA, ldsB, acc);
  }
  int t = threadIdx.x, lane = t & 63, wave = t >> 6;
  int quad = lane >> 4, r = lane & 15, wm = wave >> 2, wn = wave & 3;
  if (kh == 0){
    #pragma unroll
    for (int ni = 0; ni < 4; ni++){
      int col = n0 + wn * 64 + ni * 16 + r;
      float bias = sb2[col];
      if (ew[0] > 0.f) bias += ew[0] * eb2[(size_t)emat[0] * DD + col];
      if (ew[1] > 0.f) bias += ew[1] * eb2[(size_t)emat[1] * DD + col];
      #pragma unroll
      for (int mi = 0; mi < 8; mi++)
        #pragma unroll
        for (int r2 = 0; r2 < 4; r2++){
          int row = m0 + wm * 128 + mi * 16 + quad * 4 + r2;
          out[(size_t)row * DD + col] = acc[mi][ni][r2] + bias;
        }
    }
  } else {
    #pragma unroll
    for (int ni = 0; ni < 4; ni++){
      int col = n0 + wn * 64 + ni * 16 + r;
      #pragma unroll
      for (int mi = 0; mi < 8; mi++)
        #pragma unroll
        for (int r2 = 0; r2 < 4; r2++){
          int row = m0 + wm * 128 + mi * 16 + quad * 4 + r2;
          p1[(size_t)row * DD + col] = acc[mi][ni][r2];
        }
    }
  }
}

// ---------------------------------------------------------------- K3r: out += p1
__global__ __launch_bounds__(256) void k3r_reduce(float* __restrict__ out,
                                                  const float* __restrict__ p1){
  size_t i = (size_t)blockIdx.x * 256 + threadIdx.x;
  float4 a = ((const float4*)out)[i];
  float4 b = ((const float4*)p1)[i];
  a.x += b.x; a.y += b.y; a.z += b.z; a.w += b.w;
  ((float4*)out)[i] = a;
}

// ---------------------------------------------------------------- launch
extern "C" void kernel_launch(void* const* d_in, const int* in_sizes, int n_in,
                              void* d_out, int out_size, void* d_ws, size_t ws_size,
                              hipStream_t stream){
  const float* X   = (const float*)d_in[0];   // context_c (8,768,1024)
  const float* tc  = (const float*)d_in[1];   // time_cond (8,1024)
  const float* gw  = (const float*)d_in[2];   // gate_w (3072,4)
  const float* gb  = (const float*)d_in[3];   // gate_b (4)
  const float* tw  = (const float*)d_in[4];   // time_w (1024,8)
  const float* tb  = (const float*)d_in[5];   // time_b (8)
  const float* ew1 = (const float*)d_in[6];   // (4,1024,4096)
  const float* eb1 = (const float*)d_in[7];   // (4,4096)
  const float* ew2 = (const float*)d_in[8];   // (4,4096,1024)
  const float* eb2 = (const float*)d_in[9];   // (4,1024)
  const float* sw1 = (const float*)d_in[10];  // (1024,4096)
  const float* sb1 = (const float*)d_in[11];  // (4096)
  const float* sw2 = (const float*)d_in[12];  // (4096,1024)
  const float* sb2 = (const float*)d_in[13];  // (1024)
  float* out = (float*)d_out;
  char* ws = (char*)d_ws;

  const size_t off_part = 0;                         // 8*24*1024*4 = 786432
  const size_t off_wtop = 786432;                    // 64 B
  const size_t off_itop = 786560;                    // 64 B
  const size_t off_xb   = 1ull << 20;                // 6144*1024*2 = 12,582,912
  const size_t off_w1t  = 14ull << 20;               // 5*4096*1024*2 = 41,943,040
  const size_t off_w2t  = off_w1t + 41943040ull;     // 41,943,040
  const size_t off_h    = off_w2t + 41943040ull;     // 3*6144*4096*2 = 150,994,944
  const size_t need     = off_h + 150994944ull;      // ~238 MiB
  if (ws_size < need) return;

  float* part = (float*)(ws + off_part);
  float* wtop = (float*)(ws + off_wtop);
  int*   itop = (int*)(ws + off_itop);
  unsigned short* Xb  = (unsigned short*)(ws + off_xb);
  unsigned short* w1t = (unsigned short*)(ws + off_w1t);
  unsigned short* w2t = (unsigned short*)(ws + off_w2t);
  unsigned short* Hws = (unsigned short*)(ws + off_h);
  float* p1 = (float*)(ws + off_w1t);  // aliases w1t: dead after k2, reused by k3a

  // K1x: X fp32 -> bf16 + gating partial sums (single pass over X)
  k1x_cvt_partial<<<dim3(24, 8), 256, 0, stream>>>(X, Xb, part);
  // K0: weight transpose+convert
  k0_transpose<<<dim3(64, 16, 5), 256, 0, stream>>>(ew1, sw1, w1t, 1024, 4096);
  k0_transpose<<<dim3(16, 64, 5), 256, 0, stream>>>(ew2, sw2, w2t, 4096, 1024);
  // K1b: gating finalize (fp32 exact)
  k1b_gate<<<dim3(8), 256, 0, stream>>>(part, tc, gw, gb, tw, tb, wtop, itop);
  // K2: X @ W1 + b1 -> gelu -> *w_eff -> H (3 slots); 256^2 8-phase core
  k2_gemm1<<<dim3(24, 16, 3), 512, 0, stream>>>(Xb, w1t, eb1, sb1, wtop, itop, Hws);
  // K3a: slots in-block, z = K-half; kh=0 -> out(+bias), kh=1 -> p1
  k3a_gemm2<<<dim3(24, 4, 2), 512, 0, stream>>>(Hws, w2t, eb2, sb2, wtop, itop, out, p1);
  // K3r: out += p1
  k3r_reduce<<<dim3(6144), 256, 0, stream>>>(out, p1);
}